// Round 2
// baseline (36997.632 us; speedup 1.0000x reference)
//
#include <hip/hip_runtime.h>
#include <math.h>

#define B_ 32
#define T_ 512
#define D_ 512
#define H_ 512
#define G_ 2048        // 4*H
#define M_ (B_ * T_)   // 16384

#define UNITS_ 16      // hidden units per slice
#define COLS_ 64       // gate columns per slice (UNITS_*4)
#define BG_ 8          // batches per workgroup
#define NBG 4          // batch groups (32/8)
#define NSLICE 32      // column slices per dir (512/16)

// -----------------------------------------------------------------------------
// GEMM: xs[dir][m][g] = A_dir[m][:] @ Wi_dir + bias (unchanged from round 1)
// -----------------------------------------------------------------------------
__global__ __launch_bounds__(256) void xs_gemm(
    const float* __restrict__ x, const int* __restrict__ lengths,
    const float* __restrict__ Wi_f, const float* __restrict__ bf,
    const float* __restrict__ Wi_b, const float* __restrict__ bb,
    float* __restrict__ xs)
{
  const int dir = blockIdx.z;
  const float* Wi   = dir ? Wi_b : Wi_f;
  const float* bias = dir ? bb : bf;
  float* outp = xs + (size_t)dir * ((size_t)M_ * G_);
  const int m0 = blockIdx.x * 64;
  const int n0 = blockIdx.y * 64;

  __shared__ __attribute__((aligned(16))) float As[32][68];
  __shared__ __attribute__((aligned(16))) float Bs[32][68];

  const int tid = threadIdx.x;
  const int tx = tid & 15, ty = tid >> 4;
  const int arow = tid >> 3;
  const int acol = (tid & 7) << 2;
  const int brow = tid >> 4;
  const int bcol = (tid & 15) << 2;

  size_t abase[2];
#pragma unroll
  for (int r = 0; r < 2; ++r) {
    int m = m0 + arow + r * 32;
    int bidx = m >> 9, t = m & 511;
    int s = t;
    if (dir) { int l = lengths[bidx]; s = l - 1 - t; if (s < 0) s += T_; }
    abase[r] = ((size_t)bidx * T_ + s) * D_;
  }

  float acc[4][4] = {{0.f}};

  for (int k0 = 0; k0 < D_; k0 += 32) {
#pragma unroll
    for (int r = 0; r < 2; ++r) {
      float4 av = *(const float4*)(x + abase[r] + (k0 + acol));
      int row = arow + r * 32;
      As[acol + 0][row] = av.x;
      As[acol + 1][row] = av.y;
      As[acol + 2][row] = av.z;
      As[acol + 3][row] = av.w;
    }
#pragma unroll
    for (int r = 0; r < 2; ++r) {
      int kk = brow + r * 16;
      float4 bv = *(const float4*)(Wi + (size_t)(k0 + kk) * G_ + n0 + bcol);
      *(float4*)&Bs[kk][bcol] = bv;
    }
    __syncthreads();
#pragma unroll
    for (int kk = 0; kk < 32; ++kk) {
      float4 a4 = *(const float4*)&As[kk][ty << 2];
      float4 b4 = *(const float4*)&Bs[kk][tx << 2];
      float a_[4] = {a4.x, a4.y, a4.z, a4.w};
      float b_[4] = {b4.x, b4.y, b4.z, b4.w};
#pragma unroll
      for (int i = 0; i < 4; ++i)
#pragma unroll
        for (int j = 0; j < 4; ++j)
          acc[i][j] = fmaf(a_[i], b_[j], acc[i][j]);
    }
    __syncthreads();
  }

  float4 bias4 = *(const float4*)(bias + n0 + (tx << 2));
  float bb4[4] = {bias4.x, bias4.y, bias4.z, bias4.w};
#pragma unroll
  for (int i = 0; i < 4; ++i) {
    int m = m0 + (ty << 2) + i;
    float4 o;
    o.x = acc[i][0] + bb4[0];
    o.y = acc[i][1] + bb4[1];
    o.z = acc[i][2] + bb4[2];
    o.w = acc[i][3] + bb4[3];
    *(float4*)(outp + (size_t)m * G_ + n0 + (tx << 2)) = o;
  }
}

// zero the spin-barrier state (1024 ints) each launch
__global__ void zero_ctr(int* p) { p[threadIdx.x] = 0; }

// -----------------------------------------------------------------------------
// Recurrence v2: 256 WGs (1/CU), LDS-resident weight slices.
// WG = (dir, slice of 16 hidden units = 64 gate cols, group of 8 batches).
// h is exchanged between WGs through `out` (each step's h IS an output row).
// Per step: stage h (16KB) -> 512 threads x 1 dot(512) from LDS weights ->
// gate phase (128 threads, c in regs) -> device-scope 32-WG spin barrier.
// -----------------------------------------------------------------------------
__global__ __launch_bounds__(512) void lstm_rec2(
    const float* __restrict__ xs, const float* __restrict__ Wh_f,
    const float* __restrict__ Wh_b, const int* __restrict__ lengths,
    float* __restrict__ out, int* ctr)
{
  extern __shared__ float smem[];
  float* w_lds = smem;                      // [128 kc][64 j][4] = 32768 f
  float* h_lds = smem + 32768;              // [8][512] = 4096 f
  float* y_lds = smem + 32768 + 4096;       // [8][64]  = 512 f
  int*   l_sh  = (int*)(smem + 32768 + 4096 + 512);  // [8] + pad

  const int bid = blockIdx.x;
  const int combo = bid & 63;      // (dir, slice) -> XCD-stable under %8 RR
  const int bg = bid >> 6;
  const int dir = combo & 1;
  const int s = combo >> 1;
  const int Q = s * UNITS_;
  const int tid = threadIdx.x;
  const int b_l = tid >> 6;        // 0..7
  const int j   = tid & 63;        // 0..63: gate g=j>>4, unit u=j&15
  const int col = ((j >> 4) << 9) + Q + (j & 15);
  const int bat = bg * BG_ + b_l;
  const float* Wh  = dir ? Wh_b : Wh_f;
  const float* xsd = xs + (size_t)dir * ((size_t)M_ * G_);
  const int grp = dir * NBG + bg;          // 8 barrier groups of 32 WGs
  int* cnt_p = ctr + grp * 16;
  int* rnd_p = ctr + 512 + grp * 16;

  // ---- stage weight slice into LDS once (reused for all 512 steps) ----
  for (int i = 0; i < 16; ++i) {
    int id = tid + i * 512;                // chunk (kc, jj)
    int kc = id >> 6, jj = id & 63;
    int cc = ((jj >> 4) << 9) + Q + (jj & 15);
    float* dst = w_lds + (size_t)id * 4;
    const float* src = Wh + (size_t)(kc * 4) * G_ + cc;
    dst[0] = src[0];
    dst[1] = src[G_];
    dst[2] = src[2 * G_];
    dst[3] = src[3 * G_];
  }
  if (tid < BG_) l_sh[tid] = lengths[bg * BG_ + tid];
  __syncthreads();

  const int l_b = l_sh[b_l];
  float creg = 0.f;                         // cell state (tid<128 only)

  for (int t = 0; t < T_; ++t) {
    // 1. stage h[8][512] from out (previous step's rows)
    {
      int kp = (tid & 63) * 8;
      float4 h0, h1;
      if (t == 0) {
        h0 = make_float4(0.f, 0.f, 0.f, 0.f); h1 = h0;
      } else {
        int tp = t - 1;
        if (dir) { tp = l_b - t; if (tp < 0) tp += T_; }  // (l-1-(t-1)) mod T
        const float* src = out + ((size_t)bat * T_ + tp) * (2 * H_) + dir * H_ + kp;
        h0 = *(const float4*)src;
        h1 = *(const float4*)(src + 4);
      }
      *(float4*)&h_lds[b_l * 512 + kp]     = h0;
      *(float4*)&h_lds[b_l * 512 + kp + 4] = h1;
    }
    __syncthreads();

    // 2. matvec from LDS-resident weights
    float acc0 = xsd[((size_t)bat * T_ + t) * G_ + col];
    float acc1 = 0.f;
    const float* hb = h_lds + b_l * 512;
    const float* wb = w_lds + j * 4;
#pragma unroll 8
    for (int kc = 0; kc < 128; kc += 2) {
      float4 w0 = *(const float4*)(wb + (size_t)kc * 256);
      float4 h0 = *(const float4*)(hb + kc * 4);
      float4 w1 = *(const float4*)(wb + (size_t)(kc + 1) * 256);
      float4 h1 = *(const float4*)(hb + (kc + 1) * 4);
      acc0 = fmaf(h0.x, w0.x, acc0); acc0 = fmaf(h0.y, w0.y, acc0);
      acc0 = fmaf(h0.z, w0.z, acc0); acc0 = fmaf(h0.w, w0.w, acc0);
      acc1 = fmaf(h1.x, w1.x, acc1); acc1 = fmaf(h1.y, w1.y, acc1);
      acc1 = fmaf(h1.z, w1.z, acc1); acc1 = fmaf(h1.w, w1.w, acc1);
    }
    y_lds[b_l * 64 + j] = acc0 + acc1;
    __syncthreads();

    // 3. gates: tid<128 -> (batch tid>>4, unit tid&15)
    if (tid < 128) {
      const int gb = tid >> 4;
      const int gu = tid & 15;
      const float* yb = y_lds + gb * 64;
      float yi = yb[gu], yf = yb[16 + gu], yg = yb[32 + gu], yo = yb[48 + gu];
      float iv = 1.f / (1.f + expf(-yi));
      float fv = 1.f / (1.f + expf(-yf));
      float gv = tanhf(yg);
      float ov = 1.f / (1.f + expf(-yo));
      creg = fv * creg + iv * gv;
      float hv = ov * tanhf(creg);
      int tout = t;
      if (dir) { int gl = l_sh[gb]; tout = gl - 1 - t; if (tout < 0) tout += T_; }
      out[((size_t)(bg * BG_ + gb) * T_ + tout) * (2 * H_) + dir * H_ + Q + gu] = hv;
    }
    __threadfence();
    __syncthreads();

    // 4. 32-WG spin barrier per (dir, batch-group)
    if (t < T_ - 1) {
      if (tid == 0) {
        int old = atomicAdd(cnt_p, 1);
        if ((old & 31) == 31) {
          __hip_atomic_store(rnd_p, t + 1, __ATOMIC_RELEASE, __HIP_MEMORY_SCOPE_AGENT);
        } else {
          while (__hip_atomic_load(rnd_p, __ATOMIC_ACQUIRE, __HIP_MEMORY_SCOPE_AGENT) < t + 1) {}
        }
      }
      __syncthreads();
      __threadfence();
    }
  }
}

extern "C" void kernel_launch(void* const* d_in, const int* in_sizes, int n_in,
                              void* d_out, int out_size, void* d_ws, size_t ws_size,
                              hipStream_t stream) {
  const float* x       = (const float*)d_in[0];
  const int*   lengths = (const int*)d_in[1];
  const float* Wi_f    = (const float*)d_in[2];
  const float* Wh_f    = (const float*)d_in[3];
  const float* b_f     = (const float*)d_in[4];
  const float* Wi_b    = (const float*)d_in[5];
  const float* Wh_b    = (const float*)d_in[6];
  const float* b_b     = (const float*)d_in[7];
  float* out = (float*)d_out;
  float* xs  = (float*)d_ws;   // 2 * 16384 * 2048 fp32 = 256 MiB (exact ws fit)

  // barrier state parked in x (x is 32 MiB, fully consumed by xs_gemm first)
  int* ctr = (int*)((char*)d_in[0] + (16u << 20));

  dim3 g1(M_ / 64, G_ / 64, 2);
  xs_gemm<<<g1, 256, 0, stream>>>(x, lengths, Wi_f, b_f, Wi_b, b_b, xs);
  zero_ctr<<<1, 1024, 0, stream>>>(ctr);

  const size_t smem = (32768 + 4096 + 512 + 16) * sizeof(float);  // 146.1 KiB
  hipFuncSetAttribute((const void*)lstm_rec2,
                      hipFuncAttributeMaxDynamicSharedMemorySize, (int)smem);
  lstm_rec2<<<dim3(256), 512, smem, stream>>>(xs, Wh_f, Wh_b, lengths, out, ctr);
}

// Round 3
// 9561.192 us; speedup vs baseline: 3.8696x; 3.8696x over previous
//
#include <hip/hip_runtime.h>
#include <hip/hip_bf16.h>
#include <math.h>

#define B_ 32
#define T_ 512
#define D_ 512
#define H_ 512
#define G_ 2048        // 4*H
#define M_ (B_ * T_)   // 16384

static __device__ __forceinline__ unsigned short f2bf(float f) {
  __hip_bfloat16 h = __float2bfloat16(f);   // RNE
  return *reinterpret_cast<unsigned short*>(&h);
}
static __device__ __forceinline__ float bflo(unsigned int u) {
  return __uint_as_float(u << 16);
}
static __device__ __forceinline__ float bfhi(unsigned int u) {
  return __uint_as_float(u & 0xffff0000u);
}
static __device__ __forceinline__ unsigned int packbf2(float a, float b) {
  return (unsigned int)f2bf(a) | ((unsigned int)f2bf(b) << 16);
}

// -----------------------------------------------------------------------------
// Pack Wh (fp32 [512][2048]) -> wpack bf16 [dir][kp=256][c=2048][2]
// uint at (dir,kp,c): lo = Wh[2kp][c], hi = Wh[2kp+1][c]
// -----------------------------------------------------------------------------
__global__ __launch_bounds__(512) void pack_wh(
    const float* __restrict__ Wh_f, const float* __restrict__ Wh_b,
    unsigned int* __restrict__ wpack)
{
  int gid = blockIdx.x * 512 + threadIdx.x;    // 0 .. 2*256*2048-1
  int c   = gid & 2047;
  int kp  = (gid >> 11) & 255;
  int dir = gid >> 19;
  const float* Wh = dir ? Wh_b : Wh_f;
  const float* src = Wh + (size_t)(2 * kp) * G_ + c;
  wpack[gid] = packbf2(src[0], src[G_]);
}

// -----------------------------------------------------------------------------
// GEMM: xs[dir][m][g] = A_dir[m][:] @ Wi_dir + bias  -> bf16 output
// -----------------------------------------------------------------------------
__global__ __launch_bounds__(256) void xs_gemm(
    const float* __restrict__ x, const int* __restrict__ lengths,
    const float* __restrict__ Wi_f, const float* __restrict__ bf,
    const float* __restrict__ Wi_b, const float* __restrict__ bb,
    unsigned int* __restrict__ xs)   // bf16 pairs
{
  const int dir = blockIdx.z;
  const float* Wi   = dir ? Wi_b : Wi_f;
  const float* bias = dir ? bb : bf;
  unsigned int* outp = xs + (size_t)dir * ((size_t)M_ * (G_ / 2));
  const int m0 = blockIdx.x * 64;
  const int n0 = blockIdx.y * 64;

  __shared__ __attribute__((aligned(16))) float As[32][68];
  __shared__ __attribute__((aligned(16))) float Bs[32][68];

  const int tid = threadIdx.x;
  const int tx = tid & 15, ty = tid >> 4;
  const int arow = tid >> 3;
  const int acol = (tid & 7) << 2;
  const int brow = tid >> 4;
  const int bcol = (tid & 15) << 2;

  size_t abase[2];
#pragma unroll
  for (int r = 0; r < 2; ++r) {
    int m = m0 + arow + r * 32;
    int bidx = m >> 9, t = m & 511;
    int s = t;
    if (dir) { int l = lengths[bidx]; s = l - 1 - t; if (s < 0) s += T_; }
    abase[r] = ((size_t)bidx * T_ + s) * D_;
  }

  float acc[4][4] = {{0.f}};

  for (int k0 = 0; k0 < D_; k0 += 32) {
#pragma unroll
    for (int r = 0; r < 2; ++r) {
      float4 av = *(const float4*)(x + abase[r] + (k0 + acol));
      int row = arow + r * 32;
      As[acol + 0][row] = av.x;
      As[acol + 1][row] = av.y;
      As[acol + 2][row] = av.z;
      As[acol + 3][row] = av.w;
    }
#pragma unroll
    for (int r = 0; r < 2; ++r) {
      int kk = brow + r * 16;
      float4 bv = *(const float4*)(Wi + (size_t)(k0 + kk) * G_ + n0 + bcol);
      *(float4*)&Bs[kk][bcol] = bv;
    }
    __syncthreads();
#pragma unroll
    for (int kk = 0; kk < 32; ++kk) {
      float4 a4 = *(const float4*)&As[kk][ty << 2];
      float4 b4 = *(const float4*)&Bs[kk][tx << 2];
      float a_[4] = {a4.x, a4.y, a4.z, a4.w};
      float b_[4] = {b4.x, b4.y, b4.z, b4.w};
#pragma unroll
      for (int i = 0; i < 4; ++i)
#pragma unroll
        for (int j = 0; j < 4; ++j)
          acc[i][j] = fmaf(a_[i], b_[j], acc[i][j]);
    }
    __syncthreads();
  }

  float4 bias4 = *(const float4*)(bias + n0 + (tx << 2));
  float bb4[4] = {bias4.x, bias4.y, bias4.z, bias4.w};
#pragma unroll
  for (int i = 0; i < 4; ++i) {
    int m = m0 + (ty << 2) + i;
    uint2 o;
    o.x = packbf2(acc[i][0] + bb4[0], acc[i][1] + bb4[1]);
    o.y = packbf2(acc[i][2] + bb4[2], acc[i][3] + bb4[3]);
    *(uint2*)(outp + (size_t)m * (G_ / 2) + ((n0 + (tx << 2)) >> 1)) = o;
  }
}

// -----------------------------------------------------------------------------
// Recurrence v3: sync-free (1 WG per (batch,dir), 64 WGs), bf16 packed weights
// streamed from L2 (dir-per-XCD-half affinity keeps 2 MB working set resident).
// Thread q computes y[4q..4q+3]; per kp iter: one uint4 = 4 cols x 2 k-rows.
// h kept in LDS (fp32), c in a register.
// -----------------------------------------------------------------------------
__global__ __launch_bounds__(512) void lstm_rec3(
    const unsigned int* __restrict__ xs,      // bf16 pairs
    const unsigned int* __restrict__ wpack,   // bf16 pairs
    const int* __restrict__ lengths,
    float* __restrict__ out)
{
  // XCD affinity (8-XCD round-robin assumed): bid&7 in 0..3 -> fwd, 4..7 -> bwd
  const int bid = blockIdx.x;
  const int x7 = bid & 7;
  const int dir = x7 >> 2;
  const int b = (x7 & 3) * 8 + (bid >> 3);

  __shared__ __attribute__((aligned(16))) float h_lds[H_];
  __shared__ __attribute__((aligned(16))) float y_lds[G_];

  const int tid = threadIdx.x;                 // q = tid, cols 4q..4q+3
  const unsigned int* wq  = wpack + (size_t)dir * (256u * 2048u) + 4 * tid;
  const unsigned int* xsd = xs + (size_t)dir * ((size_t)M_ * (G_ / 2))
                               + (size_t)b * T_ * (G_ / 2) + 2 * tid;
  const int l = lengths[b];

  h_lds[tid] = 0.f;
  float c = 0.f;
  __syncthreads();

  for (int t = 0; t < T_; ++t) {
    // init acc from xs row (4 bf16 = uint2)
    uint2 xv = *(const uint2*)(xsd + (size_t)t * (G_ / 2));
    float4 acc;
    acc.x = bflo(xv.x); acc.y = bfhi(xv.x);
    acc.z = bflo(xv.y); acc.w = bfhi(xv.y);

    const unsigned int* wp = wq;
#pragma unroll 4
    for (int kp = 0; kp < 256; ++kp) {
      uint4 w = *(const uint4*)wp;
      wp += 2048;
      float h0 = h_lds[2 * kp];
      float h1 = h_lds[2 * kp + 1];
      acc.x = fmaf(h0, bflo(w.x), acc.x); acc.x = fmaf(h1, bfhi(w.x), acc.x);
      acc.y = fmaf(h0, bflo(w.y), acc.y); acc.y = fmaf(h1, bfhi(w.y), acc.y);
      acc.z = fmaf(h0, bflo(w.z), acc.z); acc.z = fmaf(h1, bfhi(w.z), acc.z);
      acc.w = fmaf(h0, bflo(w.w), acc.w); acc.w = fmaf(h1, bfhi(w.w), acc.w);
    }
    *(float4*)&y_lds[4 * tid] = acc;
    __syncthreads();

    // gates: thread tid owns hidden unit tid
    float yi = y_lds[tid];
    float yf = y_lds[H_ + tid];
    float yg = y_lds[2 * H_ + tid];
    float yo = y_lds[3 * H_ + tid];
    float iv = 1.f / (1.f + expf(-yi));
    float fv = 1.f / (1.f + expf(-yf));
    float gv = tanhf(yg);
    float ov = 1.f / (1.f + expf(-yo));
    c = fv * c + iv * gv;
    float hv = ov * tanhf(c);
    h_lds[tid] = hv;

    int tout = t;
    if (dir) { tout = l - 1 - t; if (tout < 0) tout += T_; }
    out[((size_t)b * T_ + tout) * (2 * H_) + dir * H_ + tid] = hv;
    __syncthreads();
  }
}

extern "C" void kernel_launch(void* const* d_in, const int* in_sizes, int n_in,
                              void* d_out, int out_size, void* d_ws, size_t ws_size,
                              hipStream_t stream) {
  const float* x       = (const float*)d_in[0];
  const int*   lengths = (const int*)d_in[1];
  const float* Wi_f    = (const float*)d_in[2];
  const float* Wh_f    = (const float*)d_in[3];
  const float* b_f     = (const float*)d_in[4];
  const float* Wi_b    = (const float*)d_in[5];
  const float* Wh_b    = (const float*)d_in[6];
  const float* b_b     = (const float*)d_in[7];
  float* out = (float*)d_out;

  unsigned int* xs    = (unsigned int*)d_ws;                       // 128 MiB bf16
  unsigned int* wpack = (unsigned int*)((char*)d_ws + (size_t)(M_) * G_ * 2 * 2); // +8 MiB

  pack_wh<<<dim3(2048), 512, 0, stream>>>(Wh_f, Wh_b, wpack);

  dim3 g1(M_ / 64, G_ / 64, 2);
  xs_gemm<<<g1, 256, 0, stream>>>(x, lengths, Wi_f, b_f, Wi_b, b_b, xs);

  lstm_rec3<<<dim3(64), 512, 0, stream>>>(xs, wpack, lengths, out);
}